// Round 2
// baseline (174.891 us; speedup 1.0000x reference)
//
#include <hip/hip_runtime.h>

#define Bn 8
#define Ln 256
#define Dn 128
#define Hn 6
#define En 32
#define WXROW (Hn + 2*Dn + En)   // 294
#define ROWS 8                   // i-rows per k_gcn block

// -------- Kernel 1: gcn + out + n1/n2 --------
// grid = B * (L/ROWS) blocks, 128 threads (d)
__global__ __launch_bounds__(128) void k_gcn(
    const float* __restrict__ x, const float* __restrict__ wadj,
    const float* __restrict__ W_w, const float* __restrict__ W_b,
    const float* __restrict__ Wx_w,
    const float* __restrict__ Wxx_w, const float* __restrict__ Wxx_b,
    float* __restrict__ out, float* __restrict__ n1_ws, float* __restrict__ n2_ws)
{
    __shared__ float adj[ROWS][Ln];   // 8 KB
    __shared__ float t_s[ROWS][Dn];   // 4 KB
    __shared__ float g_s[ROWS][Dn];   // 4 KB

    const int t  = threadIdx.x;
    const int b  = blockIdx.x >> 5;            // 32 blocks per batch
    const int i0 = (blockIdx.x & 31) * ROWS;

    // 1) adj[r][j] = mean_h wadj[b,h,i0+r,j]
    const float inv_h = 1.0f / 6.0f;
    for (int idx = t; idx < ROWS * Ln; idx += 128) {
        const int r = idx >> 8, jj = idx & 255;
        float s = 0.f;
        #pragma unroll
        for (int h = 0; h < Hn; ++h)
            s += wadj[(((size_t)b * Hn + h) * Ln + (i0 + r)) * Ln + jj];
        adj[r][jj] = s * inv_h;
    }
    __syncthreads();

    // 2) t_s[r][d] = sum_j adj[r][j] * x[b,j,d]
    {
        float acc[ROWS];
        #pragma unroll
        for (int r = 0; r < ROWS; ++r) acc[r] = 0.f;
        const float* xp = x + (size_t)b * Ln * Dn + t;
        #pragma unroll 4
        for (int j = 0; j < Ln; ++j) {
            const float xv = xp[(size_t)j * Dn];
            #pragma unroll
            for (int r = 0; r < ROWS; ++r)
                acc[r] = fmaf(adj[r][j], xv, acc[r]);
        }
        #pragma unroll
        for (int r = 0; r < ROWS; ++r) t_s[r][t] = acc[r];
    }
    __syncthreads();

    // 3) g_s[r][d=t] = relu(sum_c t_s[r][c] * W_w[t,c] + W_b[t])
    {
        float acc[ROWS];
        const float bias = W_b[t];
        #pragma unroll
        for (int r = 0; r < ROWS; ++r) acc[r] = bias;
        const float4* wr = (const float4*)(W_w + (size_t)t * Dn);
        #pragma unroll 8
        for (int c = 0; c < Dn / 4; ++c) {
            const float4 w = wr[c];
            const int base = c * 4;
            #pragma unroll
            for (int r = 0; r < ROWS; ++r) {
                float a = acc[r];
                a = fmaf(t_s[r][base + 0], w.x, a);
                a = fmaf(t_s[r][base + 1], w.y, a);
                a = fmaf(t_s[r][base + 2], w.z, a);
                a = fmaf(t_s[r][base + 3], w.w, a);
                acc[r] = a;
            }
        }
        #pragma unroll
        for (int r = 0; r < ROWS; ++r) g_s[r][t] = fmaxf(acc[r], 0.f);
    }
    __syncthreads();

    // 4) out[b,i0+r,d=t] = sum_c g_s[r][c] * Wxx_w[t,c] + Wxx_b[t]
    {
        float acc[ROWS];
        const float bias = Wxx_b[t];
        #pragma unroll
        for (int r = 0; r < ROWS; ++r) acc[r] = bias;
        const float4* wr = (const float4*)(Wxx_w + (size_t)t * Dn);
        #pragma unroll 8
        for (int c = 0; c < Dn / 4; ++c) {
            const float4 w = wr[c];
            const int base = c * 4;
            #pragma unroll
            for (int r = 0; r < ROWS; ++r) {
                float a = acc[r];
                a = fmaf(g_s[r][base + 0], w.x, a);
                a = fmaf(g_s[r][base + 1], w.y, a);
                a = fmaf(g_s[r][base + 2], w.z, a);
                a = fmaf(g_s[r][base + 3], w.w, a);
                acc[r] = a;
            }
        }
        #pragma unroll
        for (int r = 0; r < ROWS; ++r)
            out[((size_t)b * Ln + (i0 + r)) * Dn + t] = acc[r];
    }

    // 5) n1[b,k,i0+r] = g_s[r]·Wn1[k,:], n2[b,k,i0+r] = g_s[r]·Wn2[k,:]
    //    96 dot-products (ROWS * 12), one per thread t < 96
    if (t < ROWS * 2 * Hn) {
        const int r  = t / (2 * Hn);
        const int kk = t % (2 * Hn);
        const int k  = (kk < Hn) ? kk : (kk - Hn);
        const bool isn2 = (kk >= Hn);
        const float* wrow = Wx_w + (size_t)k * WXROW + Hn + (isn2 ? Dn : 0);
        float acc = 0.f;
        #pragma unroll 8
        for (int c = 0; c < Dn; ++c)
            acc = fmaf(g_s[r][c], wrow[c], acc);
        const size_t idx = ((size_t)b * Hn + k) * Ln + (i0 + r);
        if (isn2) n2_ws[idx] = acc;
        else      n1_ws[idx] = acc;
    }
}

// -------- Kernel 2: new_adj --------
// grid = B*L blocks (b,i), 256 threads (j)
__global__ __launch_bounds__(256) void k_adj(
    const float* __restrict__ wadj, const float* __restrict__ e,
    const float* __restrict__ Wx_w, const float* __restrict__ Wx_b,
    const float* __restrict__ n1_ws, const float* __restrict__ n2_ws,
    float* __restrict__ new_adj)
{
    __shared__ float Wa_s[Hn][Hn];
    __shared__ float We_s[Hn][En];
    __shared__ float bias_n1[Hn];   // Wx_b[k] + n1[b,k,i]

    const int t = threadIdx.x;
    const int b = blockIdx.x >> 8;
    const int i = blockIdx.x & 255;

    if (t < Hn * Hn) {
        const int k = t / Hn, h = t % Hn;
        Wa_s[k][h] = Wx_w[(size_t)k * WXROW + h];
    }
    if (t >= 64 && t < 64 + Hn * En) {
        const int q = t - 64, k = q / En, c = q % En;
        We_s[k][c] = Wx_w[(size_t)k * WXROW + Hn + 2 * Dn + c];
    }
    if (t >= 32 && t < 32 + Hn) {
        const int k = t - 32;
        bias_n1[k] = Wx_b[k] + n1_ws[((size_t)b * Hn + k) * Ln + i];
    }
    __syncthreads();

    const int j = t;

    // e[b,i,j,:] : 32 floats = 128 B contiguous per thread
    float ev[En];
    {
        const float4* ep = (const float4*)(e + (((size_t)b * Ln + i) * Ln + j) * En);
        #pragma unroll
        for (int c = 0; c < En / 4; ++c) {
            const float4 v = ep[c];
            ev[c * 4 + 0] = v.x;
            ev[c * 4 + 1] = v.y;
            ev[c * 4 + 2] = v.z;
            ev[c * 4 + 3] = v.w;
        }
    }

    float wv[Hn];
    #pragma unroll
    for (int h = 0; h < Hn; ++h)
        wv[h] = wadj[(((size_t)b * Hn + h) * Ln + i) * Ln + j];

    float n2v[Hn];
    #pragma unroll
    for (int k = 0; k < Hn; ++k)
        n2v[k] = n2_ws[((size_t)b * Hn + k) * Ln + j];

    #pragma unroll
    for (int k = 0; k < Hn; ++k) {
        float acc = bias_n1[k] + n2v[k];
        #pragma unroll
        for (int h = 0; h < Hn; ++h)
            acc = fmaf(wv[h], Wa_s[k][h], acc);
        #pragma unroll
        for (int c = 0; c < En; ++c)
            acc = fmaf(ev[c], We_s[k][c], acc);
        new_adj[(((size_t)b * Hn + k) * Ln + i) * Ln + j] = acc;
    }
}

extern "C" void kernel_launch(void* const* d_in, const int* in_sizes, int n_in,
                              void* d_out, int out_size, void* d_ws, size_t ws_size,
                              hipStream_t stream) {
    const float* x      = (const float*)d_in[0];
    const float* wadj   = (const float*)d_in[1];
    const float* e      = (const float*)d_in[2];
    const float* W_w    = (const float*)d_in[3];
    const float* W_b    = (const float*)d_in[4];
    const float* Wx_w   = (const float*)d_in[5];
    const float* Wx_b   = (const float*)d_in[6];
    const float* Wxx_w  = (const float*)d_in[7];
    const float* Wxx_b  = (const float*)d_in[8];

    float* out      = (float*)d_out;                   // (B,L,D)
    float* new_adj  = out + (size_t)Bn * Ln * Dn;      // (B,H,L,L)

    float* n1_ws = (float*)d_ws;                       // (B,H,L)
    float* n2_ws = n1_ws + (size_t)Bn * Hn * Ln;       // (B,H,L)

    k_gcn<<<Bn * (Ln / ROWS), 128, 0, stream>>>(x, wadj, W_w, W_b, Wx_w,
                                                Wxx_w, Wxx_b, out, n1_ws, n2_ws);
    k_adj<<<Bn * Ln, 256, 0, stream>>>(wadj, e, Wx_w, Wx_b, n1_ws, n2_ws, new_adj);
}

// Round 3
// 154.316 us; speedup vs baseline: 1.1333x; 1.1333x over previous
//
#include <hip/hip_runtime.h>

#define Bn 8
#define Ln 256
#define Dn 128
#define Hn 6
#define En 32
#define WXROW (Hn + 2*Dn + En)   // 294
#define ROWS 4                   // i-rows per k_gcn block

// -------- Kernel 1: gcn + out + n1/n2 --------
// grid = B * (L/ROWS) = 512 blocks, 256 threads = (s in {0,1}) x (d in 0..127)
__global__ __launch_bounds__(256) void k_gcn(
    const float* __restrict__ x, const float* __restrict__ wadj,
    const float* __restrict__ W_w, const float* __restrict__ W_b,
    const float* __restrict__ Wx_w,
    const float* __restrict__ Wxx_w, const float* __restrict__ Wxx_b,
    float* __restrict__ out, float* __restrict__ n1_ws, float* __restrict__ n2_ws)
{
    __shared__ float adj[ROWS][Ln];       // 4 KB
    __shared__ float part[2][ROWS][Dn];   // 4 KB
    __shared__ float t_s[ROWS][Dn];       // 2 KB
    __shared__ float g_s[ROWS][Dn];       // 2 KB

    const int t  = threadIdx.x;
    const int s  = t >> 7;        // j-half
    const int d  = t & 127;
    const int b  = blockIdx.x >> 6;            // 64 blocks per batch
    const int i0 = (blockIdx.x & 63) * ROWS;

    // 1) adj[r][j] = mean_h wadj[b,h,i0+r,j]   (1024 entries, 4 per thread)
    const float inv_h = 1.0f / 6.0f;
    #pragma unroll
    for (int rep = 0; rep < ROWS; ++rep) {
        const int idx = t + rep * 256;
        const int r = idx >> 8, jj = idx & 255;
        float sum = 0.f;
        #pragma unroll
        for (int h = 0; h < Hn; ++h)
            sum += wadj[(((size_t)b * Hn + h) * Ln + (i0 + r)) * Ln + jj];
        adj[r][jj] = sum * inv_h;
    }
    __syncthreads();

    // 2) partial t over j-half s:  part[s][r][d] = sum_{j in half} adj[r][j]*x[b,j,d]
    {
        float acc[ROWS];
        #pragma unroll
        for (int r = 0; r < ROWS; ++r) acc[r] = 0.f;
        const float* xp = x + (size_t)b * Ln * Dn + d;
        const int j0 = s * 128;
        #pragma unroll 4
        for (int jj = 0; jj < 128; ++jj) {
            const int j = j0 + jj;
            const float xv = xp[(size_t)j * Dn];
            #pragma unroll
            for (int r = 0; r < ROWS; ++r)
                acc[r] = fmaf(adj[r][j], xv, acc[r]);
        }
        #pragma unroll
        for (int r = 0; r < ROWS; ++r) part[s][r][d] = acc[r];
    }
    __syncthreads();

    // combine halves: thread (s,d) handles r = s and r = s+2
    {
        const int r0 = s, r1 = s + 2;
        t_s[r0][d] = part[0][r0][d] + part[1][r0][d];
        t_s[r1][d] = part[0][r1][d] + part[1][r1][d];
    }
    __syncthreads();

    // 3) g[r][d] = relu(sum_c t_s[r][c]*W_w[d,c] + W_b[d]) for r in {s, s+2}
    {
        const int r0 = s, r1 = s + 2;
        float a0 = W_b[d], a1 = a0;
        const float4* wr = (const float4*)(W_w + (size_t)d * Dn);
        #pragma unroll 8
        for (int c4 = 0; c4 < Dn / 4; ++c4) {
            const float4 w = wr[c4];
            const int c = c4 * 4;
            a0 = fmaf(t_s[r0][c+0], w.x, a0);
            a0 = fmaf(t_s[r0][c+1], w.y, a0);
            a0 = fmaf(t_s[r0][c+2], w.z, a0);
            a0 = fmaf(t_s[r0][c+3], w.w, a0);
            a1 = fmaf(t_s[r1][c+0], w.x, a1);
            a1 = fmaf(t_s[r1][c+1], w.y, a1);
            a1 = fmaf(t_s[r1][c+2], w.z, a1);
            a1 = fmaf(t_s[r1][c+3], w.w, a1);
        }
        g_s[r0][d] = fmaxf(a0, 0.f);
        g_s[r1][d] = fmaxf(a1, 0.f);
    }
    __syncthreads();

    // 4) out[b,i0+r,d] = sum_c g_s[r][c]*Wxx_w[d,c] + Wxx_b[d] for r in {s, s+2}
    {
        const int r0 = s, r1 = s + 2;
        float a0 = Wxx_b[d], a1 = a0;
        const float4* wr = (const float4*)(Wxx_w + (size_t)d * Dn);
        #pragma unroll 8
        for (int c4 = 0; c4 < Dn / 4; ++c4) {
            const float4 w = wr[c4];
            const int c = c4 * 4;
            a0 = fmaf(g_s[r0][c+0], w.x, a0);
            a0 = fmaf(g_s[r0][c+1], w.y, a0);
            a0 = fmaf(g_s[r0][c+2], w.z, a0);
            a0 = fmaf(g_s[r0][c+3], w.w, a0);
            a1 = fmaf(g_s[r1][c+0], w.x, a1);
            a1 = fmaf(g_s[r1][c+1], w.y, a1);
            a1 = fmaf(g_s[r1][c+2], w.z, a1);
            a1 = fmaf(g_s[r1][c+3], w.w, a1);
        }
        out[((size_t)b * Ln + (i0 + r0)) * Dn + d] = a0;
        out[((size_t)b * Ln + (i0 + r1)) * Dn + d] = a1;
    }

    // 5) n1/n2: ROWS*12 = 48 dot-products of length 128
    if (t < ROWS * 2 * Hn) {
        const int r  = t / (2 * Hn);
        const int kk = t % (2 * Hn);
        const int k  = (kk < Hn) ? kk : (kk - Hn);
        const bool isn2 = (kk >= Hn);
        const float* wrow = Wx_w + (size_t)k * WXROW + Hn + (isn2 ? Dn : 0);
        float acc = 0.f;
        #pragma unroll 8
        for (int c = 0; c < Dn; ++c)
            acc = fmaf(g_s[r][c], wrow[c], acc);
        const size_t idx = ((size_t)b * Hn + k) * Ln + (i0 + r);
        if (isn2) n2_ws[idx] = acc;
        else      n1_ws[idx] = acc;
    }
}

// -------- Kernel 2: new_adj --------
// grid = B*L blocks (b,i), 256 threads (j)
#define EPAD 33
__global__ __launch_bounds__(256) void k_adj(
    const float* __restrict__ wadj, const float* __restrict__ e,
    const float* __restrict__ Wx_w, const float* __restrict__ Wx_b,
    const float* __restrict__ n1_ws, const float* __restrict__ n2_ws,
    float* __restrict__ new_adj)
{
    __shared__ float e_lds[Ln * EPAD];   // 33 KB, padded stride 33
    __shared__ float Wa_s[Hn][Hn];
    __shared__ float We_s[Hn][En];
    __shared__ float bias_n1[Hn];        // Wx_b[k] + n1[b,k,i]

    const int t = threadIdx.x;
    const int b = blockIdx.x >> 8;
    const int i = blockIdx.x & 255;

    if (t < Hn * Hn) {
        const int k = t / Hn, h = t % Hn;
        Wa_s[k][h] = Wx_w[(size_t)k * WXROW + h];
    }
    if (t >= 64 && t < 64 + Hn * En) {
        const int q = t - 64, k = q / En, c = q % En;
        We_s[k][c] = Wx_w[(size_t)k * WXROW + Hn + 2 * Dn + c];
    }
    if (t >= 32 && t < 32 + Hn) {
        const int k = t - 32;
        bias_n1[k] = Wx_b[k] + n1_ws[((size_t)b * Hn + k) * Ln + i];
    }

    // stage e[b,i,:,:] (256x32 floats = 32 KB) coalesced into padded LDS
    {
        const float4* ep4 = (const float4*)(e + (((size_t)b * Ln + i) * Ln) * En);
        #pragma unroll
        for (int k = 0; k < 8; ++k) {
            const int idx = t + k * 256;       // float4 index
            const float4 v = ep4[idx];
            const int j = idx >> 3;            // 8 float4 per j-row
            const int c = (idx & 7) * 4;
            float* dst = &e_lds[j * EPAD + c];
            dst[0] = v.x; dst[1] = v.y; dst[2] = v.z; dst[3] = v.w;
        }
    }
    __syncthreads();

    const int j = t;

    float ev[En];
    {
        const float* src = &e_lds[j * EPAD];
        #pragma unroll
        for (int c = 0; c < En; ++c) ev[c] = src[c];
    }

    float wv[Hn];
    #pragma unroll
    for (int h = 0; h < Hn; ++h)
        wv[h] = wadj[(((size_t)b * Hn + h) * Ln + i) * Ln + j];

    float n2v[Hn];
    #pragma unroll
    for (int k = 0; k < Hn; ++k)
        n2v[k] = n2_ws[((size_t)b * Hn + k) * Ln + j];

    #pragma unroll
    for (int k = 0; k < Hn; ++k) {
        float acc = bias_n1[k] + n2v[k];
        #pragma unroll
        for (int h = 0; h < Hn; ++h)
            acc = fmaf(wv[h], Wa_s[k][h], acc);
        #pragma unroll
        for (int c = 0; c < En; ++c)
            acc = fmaf(ev[c], We_s[k][c], acc);
        new_adj[(((size_t)b * Hn + k) * Ln + i) * Ln + j] = acc;
    }
}

extern "C" void kernel_launch(void* const* d_in, const int* in_sizes, int n_in,
                              void* d_out, int out_size, void* d_ws, size_t ws_size,
                              hipStream_t stream) {
    const float* x      = (const float*)d_in[0];
    const float* wadj   = (const float*)d_in[1];
    const float* e      = (const float*)d_in[2];
    const float* W_w    = (const float*)d_in[3];
    const float* W_b    = (const float*)d_in[4];
    const float* Wx_w   = (const float*)d_in[5];
    const float* Wx_b   = (const float*)d_in[6];
    const float* Wxx_w  = (const float*)d_in[7];
    const float* Wxx_b  = (const float*)d_in[8];

    float* out      = (float*)d_out;                   // (B,L,D)
    float* new_adj  = out + (size_t)Bn * Ln * Dn;      // (B,H,L,L)

    float* n1_ws = (float*)d_ws;                       // (B,H,L)
    float* n2_ws = n1_ws + (size_t)Bn * Hn * Ln;       // (B,H,L)

    k_gcn<<<Bn * (Ln / ROWS), 256, 0, stream>>>(x, wadj, W_w, W_b, Wx_w,
                                                Wxx_w, Wxx_b, out, n1_ws, n2_ws);
    k_adj<<<Bn * Ln, 256, 0, stream>>>(wadj, e, Wx_w, Wx_b, n1_ws, n2_ws, new_adj);
}

// Round 4
// 145.963 us; speedup vs baseline: 1.1982x; 1.0572x over previous
//
#include <hip/hip_runtime.h>

#define Bn 8
#define Ln 256
#define Dn 128
#define Hn 6
#define En 32
#define WXROW (Hn + 2*Dn + En)   // 294
#define ROWS 4                   // i-rows per k_gcn block

// -------- Kernel 1: gcn + out + n1/n2 --------
// grid = B * (L/ROWS) = 512 blocks, 256 threads
__global__ __launch_bounds__(256) void k_gcn(
    const float* __restrict__ x, const float* __restrict__ wadj,
    const float* __restrict__ W_w, const float* __restrict__ W_b,
    const float* __restrict__ Wx_w,
    const float* __restrict__ Wxx_w, const float* __restrict__ Wxx_b,
    float* __restrict__ out, float* __restrict__ n1_ws, float* __restrict__ n2_ws)
{
    __shared__ float adj[ROWS][Ln];        // 4 KB
    __shared__ float part[8][ROWS][Dn];    // 16 KB
    __shared__ float t_s[ROWS][Dn];        // 2 KB
    __shared__ float g_s[ROWS][Dn];        // 2 KB

    const int t  = threadIdx.x;
    const int b  = blockIdx.x >> 6;            // 64 blocks per batch
    const int i0 = (blockIdx.x & 63) * ROWS;

    // 1) adj[r][j] = mean_h wadj[b,h,i0+r,j]  — float4 per thread: (r = t>>6, j4 = t&63)
    {
        const int r  = t >> 6;
        const int j4 = t & 63;
        const float4* w4 = (const float4*)wadj;
        float4 sum = {0.f, 0.f, 0.f, 0.f};
        #pragma unroll
        for (int h = 0; h < Hn; ++h) {
            const float4 v = w4[(((size_t)b * Hn + h) * Ln + (i0 + r)) * (Ln / 4) + j4];
            sum.x += v.x; sum.y += v.y; sum.z += v.z; sum.w += v.w;
        }
        const float inv_h = 1.0f / 6.0f;
        sum.x *= inv_h; sum.y *= inv_h; sum.z *= inv_h; sum.w *= inv_h;
        ((float4*)&adj[0][0])[r * (Ln / 4) + j4] = sum;
    }
    __syncthreads();

    // 2) t[r][d] = sum_j adj[r][j] * x[b,j,d]
    //    256 thr = (q = t>>5 in 0..7: j-slice) x (d4 = t&31: float4 column)
    {
        const int q  = t >> 5;
        const int d4 = t & 31;
        float4 acc[ROWS];
        #pragma unroll
        for (int r = 0; r < ROWS; ++r) acc[r] = {0.f, 0.f, 0.f, 0.f};

        const float4* xp4 = (const float4*)(x + (size_t)b * Ln * Dn) + d4;
        const float4* adj4 = (const float4*)&adj[0][0];
        const int j0 = q * 32;

        #pragma unroll 2
        for (int jj4 = 0; jj4 < 8; ++jj4) {
            const int j = j0 + jj4 * 4;
            const float4 xv0 = xp4[(size_t)(j + 0) * 32];
            const float4 xv1 = xp4[(size_t)(j + 1) * 32];
            const float4 xv2 = xp4[(size_t)(j + 2) * 32];
            const float4 xv3 = xp4[(size_t)(j + 3) * 32];
            #pragma unroll
            for (int r = 0; r < ROWS; ++r) {
                const float4 a = adj4[r * (Ln / 4) + (j >> 2)];
                float4 v = acc[r];
                v.x = fmaf(a.x, xv0.x, v.x); v.y = fmaf(a.x, xv0.y, v.y);
                v.z = fmaf(a.x, xv0.z, v.z); v.w = fmaf(a.x, xv0.w, v.w);
                v.x = fmaf(a.y, xv1.x, v.x); v.y = fmaf(a.y, xv1.y, v.y);
                v.z = fmaf(a.y, xv1.z, v.z); v.w = fmaf(a.y, xv1.w, v.w);
                v.x = fmaf(a.z, xv2.x, v.x); v.y = fmaf(a.z, xv2.y, v.y);
                v.z = fmaf(a.z, xv2.z, v.z); v.w = fmaf(a.z, xv2.w, v.w);
                v.x = fmaf(a.w, xv3.x, v.x); v.y = fmaf(a.w, xv3.y, v.y);
                v.z = fmaf(a.w, xv3.z, v.z); v.w = fmaf(a.w, xv3.w, v.w);
                acc[r] = v;
            }
        }
        #pragma unroll
        for (int r = 0; r < ROWS; ++r)
            ((float4*)&part[q][r][0])[d4] = acc[r];
    }
    __syncthreads();

    // combine the 8 j-slices: thread handles (r = t>>7 and r+2, d = t&127)
    {
        const int d  = t & 127;
        const int rr = t >> 7;
        #pragma unroll
        for (int rq = 0; rq < 2; ++rq) {
            const int r = rr + rq * 2;
            float s = 0.f;
            #pragma unroll
            for (int q = 0; q < 8; ++q) s += part[q][r][d];
            t_s[r][d] = s;
        }
    }
    __syncthreads();

    // 3) g[r][d] = relu(sum_c t_s[r][c]*W_w[d,c] + W_b[d]) for r in {s, s+2}
    {
        const int s = t >> 7, d = t & 127;
        const int r0 = s, r1 = s + 2;
        float a0 = W_b[d], a1 = a0;
        const float4* wr = (const float4*)(W_w + (size_t)d * Dn);
        const float4* t0 = (const float4*)&t_s[r0][0];
        const float4* t1 = (const float4*)&t_s[r1][0];
        #pragma unroll 8
        for (int c4 = 0; c4 < Dn / 4; ++c4) {
            const float4 w = wr[c4];
            const float4 u0 = t0[c4];
            const float4 u1 = t1[c4];
            a0 = fmaf(u0.x, w.x, a0); a0 = fmaf(u0.y, w.y, a0);
            a0 = fmaf(u0.z, w.z, a0); a0 = fmaf(u0.w, w.w, a0);
            a1 = fmaf(u1.x, w.x, a1); a1 = fmaf(u1.y, w.y, a1);
            a1 = fmaf(u1.z, w.z, a1); a1 = fmaf(u1.w, w.w, a1);
        }
        g_s[r0][d] = fmaxf(a0, 0.f);
        g_s[r1][d] = fmaxf(a1, 0.f);
    }
    __syncthreads();

    // 4) out[b,i0+r,d] = sum_c g_s[r][c]*Wxx_w[d,c] + Wxx_b[d] for r in {s, s+2}
    {
        const int s = t >> 7, d = t & 127;
        const int r0 = s, r1 = s + 2;
        float a0 = Wxx_b[d], a1 = a0;
        const float4* wr = (const float4*)(Wxx_w + (size_t)d * Dn);
        const float4* g0 = (const float4*)&g_s[r0][0];
        const float4* g1 = (const float4*)&g_s[r1][0];
        #pragma unroll 8
        for (int c4 = 0; c4 < Dn / 4; ++c4) {
            const float4 w = wr[c4];
            const float4 u0 = g0[c4];
            const float4 u1 = g1[c4];
            a0 = fmaf(u0.x, w.x, a0); a0 = fmaf(u0.y, w.y, a0);
            a0 = fmaf(u0.z, w.z, a0); a0 = fmaf(u0.w, w.w, a0);
            a1 = fmaf(u1.x, w.x, a1); a1 = fmaf(u1.y, w.y, a1);
            a1 = fmaf(u1.z, w.z, a1); a1 = fmaf(u1.w, w.w, a1);
        }
        out[((size_t)b * Ln + (i0 + r0)) * Dn + d] = a0;
        out[((size_t)b * Ln + (i0 + r1)) * Dn + d] = a1;
    }

    // 5) n1/n2: ROWS*12 = 48 dot-products of length 128
    if (t < ROWS * 2 * Hn) {
        const int r  = t / (2 * Hn);
        const int kk = t % (2 * Hn);
        const int k  = (kk < Hn) ? kk : (kk - Hn);
        const bool isn2 = (kk >= Hn);
        const float* wrow = Wx_w + (size_t)k * WXROW + Hn + (isn2 ? Dn : 0);
        float acc = 0.f;
        #pragma unroll 8
        for (int c = 0; c < Dn; ++c)
            acc = fmaf(g_s[r][c], wrow[c], acc);
        const size_t idx = ((size_t)b * Hn + k) * Ln + (i0 + r);
        if (isn2) n2_ws[idx] = acc;
        else      n1_ws[idx] = acc;
    }
}

// -------- Kernel 2: new_adj --------
// grid = B*L blocks (b,i), 256 threads (j)
#define EPAD 33
__global__ __launch_bounds__(256) void k_adj(
    const float* __restrict__ wadj, const float* __restrict__ e,
    const float* __restrict__ Wx_w, const float* __restrict__ Wx_b,
    const float* __restrict__ n1_ws, const float* __restrict__ n2_ws,
    float* __restrict__ new_adj)
{
    __shared__ float e_lds[Ln * EPAD];   // 33 KB, padded stride 33
    __shared__ float Wa_s[Hn][Hn];
    __shared__ float We_s[Hn][En];
    __shared__ float bias_n1[Hn];        // Wx_b[k] + n1[b,k,i]

    const int t = threadIdx.x;
    const int b = blockIdx.x >> 8;
    const int i = blockIdx.x & 255;

    if (t < Hn * Hn) {
        const int k = t / Hn, h = t % Hn;
        Wa_s[k][h] = Wx_w[(size_t)k * WXROW + h];
    }
    if (t >= 64 && t < 64 + Hn * En) {
        const int q = t - 64, k = q / En, c = q % En;
        We_s[k][c] = Wx_w[(size_t)k * WXROW + Hn + 2 * Dn + c];
    }
    if (t >= 32 && t < 32 + Hn) {
        const int k = t - 32;
        bias_n1[k] = Wx_b[k] + n1_ws[((size_t)b * Hn + k) * Ln + i];
    }

    // stage e[b,i,:,:] (256x32 floats = 32 KB) coalesced into padded LDS
    {
        const float4* ep4 = (const float4*)(e + (((size_t)b * Ln + i) * Ln) * En);
        #pragma unroll
        for (int k = 0; k < 8; ++k) {
            const int idx = t + k * 256;       // float4 index
            const float4 v = ep4[idx];
            const int j = idx >> 3;            // 8 float4 per j-row
            const int c = (idx & 7) * 4;
            float* dst = &e_lds[j * EPAD + c];
            dst[0] = v.x; dst[1] = v.y; dst[2] = v.z; dst[3] = v.w;
        }
    }
    __syncthreads();

    const int j = t;

    float ev[En];
    {
        const float* src = &e_lds[j * EPAD];
        #pragma unroll
        for (int c = 0; c < En; ++c) ev[c] = src[c];
    }

    float wv[Hn];
    #pragma unroll
    for (int h = 0; h < Hn; ++h)
        wv[h] = wadj[(((size_t)b * Hn + h) * Ln + i) * Ln + j];

    float n2v[Hn];
    #pragma unroll
    for (int k = 0; k < Hn; ++k)
        n2v[k] = n2_ws[((size_t)b * Hn + k) * Ln + j];

    #pragma unroll
    for (int k = 0; k < Hn; ++k) {
        float acc = bias_n1[k] + n2v[k];
        #pragma unroll
        for (int h = 0; h < Hn; ++h)
            acc = fmaf(wv[h], Wa_s[k][h], acc);
        #pragma unroll
        for (int c = 0; c < En; ++c)
            acc = fmaf(ev[c], We_s[k][c], acc);
        new_adj[(((size_t)b * Hn + k) * Ln + i) * Ln + j] = acc;
    }
}

extern "C" void kernel_launch(void* const* d_in, const int* in_sizes, int n_in,
                              void* d_out, int out_size, void* d_ws, size_t ws_size,
                              hipStream_t stream) {
    const float* x      = (const float*)d_in[0];
    const float* wadj   = (const float*)d_in[1];
    const float* e      = (const float*)d_in[2];
    const float* W_w    = (const float*)d_in[3];
    const float* W_b    = (const float*)d_in[4];
    const float* Wx_w   = (const float*)d_in[5];
    const float* Wx_b   = (const float*)d_in[6];
    const float* Wxx_w  = (const float*)d_in[7];
    const float* Wxx_b  = (const float*)d_in[8];

    float* out      = (float*)d_out;                   // (B,L,D)
    float* new_adj  = out + (size_t)Bn * Ln * Dn;      // (B,H,L,L)

    float* n1_ws = (float*)d_ws;                       // (B,H,L)
    float* n2_ws = n1_ws + (size_t)Bn * Hn * Ln;       // (B,H,L)

    k_gcn<<<Bn * (Ln / ROWS), 256, 0, stream>>>(x, wadj, W_w, W_b, Wx_w,
                                                Wxx_w, Wxx_b, out, n1_ws, n2_ws);
    k_adj<<<Bn * Ln, 256, 0, stream>>>(wadj, e, Wx_w, Wx_b, n1_ws, n2_ws, new_adj);
}